// Round 1
// 957.658 us; speedup vs baseline: 1.4063x; 1.4063x over previous
//
#include <hip/hip_runtime.h>
#include <math.h>
#include <stdint.h>

// MultiHeadAttention: B=2,S=2048,D=768,H=12,depth=64
// out = (softmax(mask(QK^T/8)) V) Wo^T + bo ; also returns attn itself.
// d_out = [out (B*S*D) | attn (B*H*S*S)] fp32.
//
// All GEMMs use split-precision bf16 MFMA (v_mfma_f32_16x16x32_bf16):
//   x = hi + lo (bf16 each, exact Sterbenz residual), A*B ~= AhBh + AhBl + AlBh
//   -> ~2^-17 relative error, well inside the fp32-path error budget.
// A/B fragments are loaded with a consistent (group,slot)->k mapping on BOTH
// operands; since MFMA A/B layouts are mutually symmetric, the dot product is
// invariant to the k-permutation, so no dependence on the exact HW A/B layout.
// C/D layout (HW-verified): col = lane&15, row = (lane>>4)*4 + reg.
constexpr int B_ = 2, S_ = 2048, D_ = 768, H_ = 12, DP_ = 64;
constexpr int M_ = B_ * S_;                              // 4096 rows
constexpr size_t HS_ELEMS = (size_t)B_ * H_ * S_ * DP_;  // head-split tensor elems
constexpr size_t OUT_ELEMS = (size_t)M_ * D_;

typedef __bf16 bf16_t;
typedef bf16_t bf16x8 __attribute__((ext_vector_type(8)));
typedef float f32x4 __attribute__((ext_vector_type(4)));

__device__ __forceinline__ f32x4 mfma16(bf16x8 a, bf16x8 b, f32x4 c) {
  return __builtin_amdgcn_mfma_f32_16x16x32_bf16(a, b, c, 0, 0, 0);
}

__device__ __forceinline__ float truncbf(float x) {
  return __uint_as_float(__float_as_uint(x) & 0xFFFF0000u);
}
__device__ __forceinline__ uint32_t pack_hi2(float x, float y) {
  return (__float_as_uint(x) >> 16) | (__float_as_uint(y) & 0xFFFF0000u);
}
__device__ __forceinline__ uint32_t pack_lo2(float x, float y) {
  const float lx = x - truncbf(x);   // exact (Sterbenz)
  const float ly = y - truncbf(y);
  return (__float_as_uint(lx) >> 16) | (__float_as_uint(ly) & 0xFFFF0000u);
}
// 8 consecutive floats -> hi/lo planes, packed 2 bf16 per uint.
__device__ __forceinline__ void cvt8(const float4 a, const float4 b, uint4& H, uint4& L) {
  H.x = pack_hi2(a.x, a.y); H.y = pack_hi2(a.z, a.w);
  H.z = pack_hi2(b.x, b.y); H.w = pack_hi2(b.z, b.w);
  L.x = pack_lo2(a.x, a.y); L.y = pack_lo2(a.z, a.w);
  L.z = pack_lo2(b.x, b.y); L.w = pack_lo2(b.z, b.w);
}

// LDS tiles are [rows][64] bf16 (128B rows = 8 slots of 16B). Slot index is
// XOR-swizzled by (row&7): conflict-free ds_read_b128 fragment loads (T2/G4).
__device__ __forceinline__ bf16x8 ldfrag(const uint16_t (*T)[64], int row, int slot) {
  return *(const bf16x8*)&T[row][(slot ^ (row & 7)) << 3];
}

// ---------------------------------------------------------------------------
// Projections  Y = X @ W^T + bias.  X:[M,768], W:[768,768], both K-contiguous.
// 128x128 tile, BK=64, 256 threads = 4 waves (2x2 of 64x64), split-bf16 MFMA.
// MODE: 0 flat [M,768]; 1 headsplit [B,H,S,64]; 2 headsplit-transposed [B,H,64,S]
// (MODE 2 feeds PV as a K-contiguous B operand; MFMA C-frag stores it as float4).
// ---------------------------------------------------------------------------
template <int MODE>
__global__ __launch_bounds__(256) void xwt_mfma(const float* __restrict__ X,
                                                const float* __restrict__ W,
                                                const float* __restrict__ bias,
                                                float* __restrict__ Y) {
  __shared__ alignas(16) uint16_t Xh[128][64], Xl[128][64], Wh[128][64], Wl[128][64];
  const float* Xb = X + (size_t)blockIdx.x * 128 * D_;
  const float* Wb = W + (size_t)blockIdx.y * 128 * D_;
  const int t = threadIdx.x;
  const int lane = t & 63, wid = t >> 6;
  const int wm = (wid >> 1) * 64, wn = (wid & 1) * 64;
  const int r = lane & 15, g = lane >> 4;
  f32x4 acc[4][4] = {};
  for (int k0 = 0; k0 < D_; k0 += 64) {
    __syncthreads();  // protect previous iteration's fragment reads
#pragma unroll
    for (int i = 0; i < 8; ++i) {
      const int u = t + i * 256;
      const int tens = u >> 10;  // 0 = X, 1 = W (uniform per unrolled i)
      const int idx = u & 1023;
      const int row = idx >> 3, sl = idx & 7;
      const float* src = (tens ? Wb : Xb) + (size_t)row * D_ + k0 + sl * 8;
      const float4 a = *(const float4*)src;
      const float4 b = *(const float4*)(src + 4);
      uint4 H, L; cvt8(a, b, H, L);
      const int ps = (sl ^ (row & 7)) << 3;
      if (tens) { *(uint4*)&Wh[row][ps] = H; *(uint4*)&Wl[row][ps] = L; }
      else      { *(uint4*)&Xh[row][ps] = H; *(uint4*)&Xl[row][ps] = L; }
    }
    __syncthreads();
#pragma unroll
    for (int ks = 0; ks < 2; ++ks) {
      const int slot = ks * 4 + g;
      bf16x8 aH[4], aL[4], bH[4], bL[4];
#pragma unroll
      for (int mi = 0; mi < 4; ++mi) {
        const int row = wm + mi * 16 + r;
        aH[mi] = ldfrag(Xh, row, slot); aL[mi] = ldfrag(Xl, row, slot);
      }
#pragma unroll
      for (int ni = 0; ni < 4; ++ni) {
        const int row = wn + ni * 16 + r;
        bH[ni] = ldfrag(Wh, row, slot); bL[ni] = ldfrag(Wl, row, slot);
      }
#pragma unroll
      for (int mi = 0; mi < 4; ++mi)
#pragma unroll
        for (int ni = 0; ni < 4; ++ni) {
          acc[mi][ni] = mfma16(aH[mi], bH[ni], acc[mi][ni]);
          acc[mi][ni] = mfma16(aH[mi], bL[ni], acc[mi][ni]);
          acc[mi][ni] = mfma16(aL[mi], bH[ni], acc[mi][ni]);
        }
    }
  }
  const int m0 = blockIdx.x * 128 + wm;
  const int n0 = blockIdx.y * 128 + wn;
#pragma unroll
  for (int mi = 0; mi < 4; ++mi) {
    const int rowb = m0 + mi * 16 + 4 * g;  // + j
#pragma unroll
    for (int ni = 0; ni < 4; ++ni) {
      const int col = n0 + ni * 16 + r;
      const float bv = bias[col];
      if (MODE == 0) {
        float* dst = Y + (size_t)rowb * D_ + col;
#pragma unroll
        for (int j = 0; j < 4; ++j) dst[(size_t)j * D_] = acc[mi][ni][j] + bv;
      } else if (MODE == 1) {
        const int h = col >> 6, d = col & 63;
#pragma unroll
        for (int j = 0; j < 4; ++j) {
          const int m = rowb + j;
          const int b = m >> 11, s = m & (S_ - 1);
          Y[(((size_t)b * H_ + h) * S_ + s) * DP_ + d] = acc[mi][ni][j] + bv;
        }
      } else {  // MODE 2: Vt[b][h][d][s] — 4 consecutive s => float4
        const int h = col >> 6, d = col & 63;
        const int b = rowb >> 11, s = rowb & (S_ - 1);
        float4 o;
        o.x = acc[mi][ni][0] + bv; o.y = acc[mi][ni][1] + bv;
        o.z = acc[mi][ni][2] + bv; o.w = acc[mi][ni][3] + bv;
        *(float4*)(Y + (((size_t)b * H_ + h) * DP_ + d) * S_ + s) = o;
      }
    }
  }
}

// ---------------------------------------------------------------------------
// Scores: per (b,h)  P = (Q @ K^T) / 8.  Q,K: [S,64] head-split slices.
// K-depth = 64 staged in one shot; 128x128 output tile, 4 waves.
// ---------------------------------------------------------------------------
__global__ __launch_bounds__(256) void scores_mfma(const float* __restrict__ Q,
                                                   const float* __restrict__ K,
                                                   float* __restrict__ P) {
  __shared__ alignas(16) uint16_t Qh[128][64], Ql[128][64], Kh[128][64], Kl[128][64];
  const int bh = blockIdx.z;
  const float* Qb = Q + ((size_t)bh * S_ + blockIdx.x * 128) * DP_;
  const float* Kb = K + ((size_t)bh * S_ + blockIdx.y * 128) * DP_;
  const int t = threadIdx.x;
#pragma unroll
  for (int i = 0; i < 8; ++i) {
    const int u = t + i * 256;
    const int tens = u >> 10;  // 0 = Q, 1 = K
    const int idx = u & 1023;
    const int row = idx >> 3, sl = idx & 7;
    const float* src = (tens ? Kb : Qb) + (size_t)row * DP_ + sl * 8;
    const float4 a = *(const float4*)src;
    const float4 b = *(const float4*)(src + 4);
    uint4 H, L; cvt8(a, b, H, L);
    const int ps = (sl ^ (row & 7)) << 3;
    if (tens) { *(uint4*)&Kh[row][ps] = H; *(uint4*)&Kl[row][ps] = L; }
    else      { *(uint4*)&Qh[row][ps] = H; *(uint4*)&Ql[row][ps] = L; }
  }
  __syncthreads();
  const int lane = t & 63, wid = t >> 6;
  const int wm = (wid >> 1) * 64, wn = (wid & 1) * 64;
  const int r = lane & 15, g = lane >> 4;
  f32x4 acc[4][4] = {};
#pragma unroll
  for (int ks = 0; ks < 2; ++ks) {
    const int slot = ks * 4 + g;
    bf16x8 aH[4], aL[4], bH[4], bL[4];
#pragma unroll
    for (int mi = 0; mi < 4; ++mi) {
      const int row = wm + mi * 16 + r;
      aH[mi] = ldfrag(Qh, row, slot); aL[mi] = ldfrag(Ql, row, slot);
    }
#pragma unroll
    for (int ni = 0; ni < 4; ++ni) {
      const int row = wn + ni * 16 + r;
      bH[ni] = ldfrag(Kh, row, slot); bL[ni] = ldfrag(Kl, row, slot);
    }
#pragma unroll
    for (int mi = 0; mi < 4; ++mi)
#pragma unroll
      for (int ni = 0; ni < 4; ++ni) {
        acc[mi][ni] = mfma16(aH[mi], bH[ni], acc[mi][ni]);
        acc[mi][ni] = mfma16(aH[mi], bL[ni], acc[mi][ni]);
        acc[mi][ni] = mfma16(aL[mi], bH[ni], acc[mi][ni]);
      }
  }
  float* Pb = P + (size_t)bh * S_ * S_;
  const int m0 = blockIdx.x * 128 + wm, n0 = blockIdx.y * 128 + wn;
#pragma unroll
  for (int mi = 0; mi < 4; ++mi) {
    const int rowb = m0 + mi * 16 + 4 * g;
#pragma unroll
    for (int ni = 0; ni < 4; ++ni) {
      const int col = n0 + ni * 16 + r;
      float* dst = Pb + (size_t)rowb * S_ + col;
#pragma unroll
      for (int j = 0; j < 4; ++j) dst[(size_t)j * S_] = acc[mi][ni][j] * 0.125f;
    }
  }
}

// ---------------------------------------------------------------------------
// Row softmax in place over attn rows (length S), with key mask [B,1,1,S].
// One 256-thread block per row; 8 elements (2 float4) per thread. (unchanged)
// ---------------------------------------------------------------------------
__global__ __launch_bounds__(256) void softmax_rows(float* __restrict__ P,
                                                    const int* __restrict__ mask) {
  const int row = blockIdx.x;       // bh*S + q
  const int bh = row >> 11;         // /S_
  const int b = bh / H_;
  float4* p4 = (float4*)(P + (size_t)row * S_);
  const int4* m4 = (const int4*)(mask + (size_t)b * S_);
  const int t = threadIdx.x;
  __shared__ float red[8];

  float4 v[2];
  float mx = -__builtin_inff();
#pragma unroll
  for (int r = 0; r < 2; ++r) {
    const int i4 = r * 256 + t;
    float4 val = p4[i4];
    const int4 mm = m4[i4];
    if (mm.x == 0) val.x = -__builtin_inff();
    if (mm.y == 0) val.y = -__builtin_inff();
    if (mm.z == 0) val.z = -__builtin_inff();
    if (mm.w == 0) val.w = -__builtin_inff();
    v[r] = val;
    mx = fmaxf(mx, fmaxf(fmaxf(val.x, val.y), fmaxf(val.z, val.w)));
  }
#pragma unroll
  for (int o = 32; o > 0; o >>= 1) mx = fmaxf(mx, __shfl_down(mx, o));
  const int wv = t >> 6, ln = t & 63;
  if (ln == 0) red[wv] = mx;
  __syncthreads();
  mx = fmaxf(fmaxf(red[0], red[1]), fmaxf(red[2], red[3]));

  float sum = 0.f;
#pragma unroll
  for (int r = 0; r < 2; ++r) {
    float4 val = v[r];
    val.x = (val.x == -__builtin_inff()) ? 0.f : __expf(val.x - mx);
    val.y = (val.y == -__builtin_inff()) ? 0.f : __expf(val.y - mx);
    val.z = (val.z == -__builtin_inff()) ? 0.f : __expf(val.z - mx);
    val.w = (val.w == -__builtin_inff()) ? 0.f : __expf(val.w - mx);
    v[r] = val;
    sum += val.x + val.y + val.z + val.w;
  }
#pragma unroll
  for (int o = 32; o > 0; o >>= 1) sum += __shfl_down(sum, o);
  if (ln == 0) red[4 + wv] = sum;
  __syncthreads();
  sum = red[4] + red[5] + red[6] + red[7];
  const float inv = 1.0f / sum;
#pragma unroll
  for (int r = 0; r < 2; ++r) {
    float4 val = v[r];
    val.x *= inv; val.y *= inv; val.z *= inv; val.w *= inv;
    p4[r * 256 + t] = val;
  }
}

// ---------------------------------------------------------------------------
// ctx = P @ V per (b,h).  P:[S,S] (K-contiguous), Vt:[64,S] (K-contiguous).
// 64x64 tile, BK=64, 4 waves each 16 rows x 64 cols. Writes concat layout
// C[b][s][h*64+d] so the final projection is a flat GEMM.
// ---------------------------------------------------------------------------
__global__ __launch_bounds__(256) void ctx_mfma(const float* __restrict__ P,
                                                const float* __restrict__ Vt,
                                                float* __restrict__ C) {
  __shared__ alignas(16) uint16_t Ph[64][64], Pl[64][64], Vh[64][64], Vl[64][64];
  const int bh = blockIdx.y;
  const int b = bh / H_, h = bh % H_;
  const float* Pb = P + ((size_t)bh * S_ + blockIdx.x * 64) * S_;
  const float* Vb = Vt + (size_t)bh * DP_ * S_;
  const int t = threadIdx.x;
  const int lane = t & 63, wid = t >> 6;
  const int r = lane & 15, g = lane >> 4;
  f32x4 acc[4] = {};
  for (int k0 = 0; k0 < S_; k0 += 64) {
    __syncthreads();
#pragma unroll
    for (int i = 0; i < 4; ++i) {
      const int u = t + i * 256;
      const int tens = u >> 9;  // 0 = P (512 units), 1 = Vt (512 units)
      const int idx = u & 511;
      const int row = idx >> 3, sl = idx & 7;
      const float* src = (tens ? Vb : Pb) + (size_t)row * S_ + k0 + sl * 8;
      const float4 a = *(const float4*)src;
      const float4 bq = *(const float4*)(src + 4);
      uint4 H, L; cvt8(a, bq, H, L);
      const int ps = (sl ^ (row & 7)) << 3;
      if (tens) { *(uint4*)&Vh[row][ps] = H; *(uint4*)&Vl[row][ps] = L; }
      else      { *(uint4*)&Ph[row][ps] = H; *(uint4*)&Pl[row][ps] = L; }
    }
    __syncthreads();
#pragma unroll
    for (int ks = 0; ks < 2; ++ks) {
      const int slot = ks * 4 + g;
      const int arow = wid * 16 + r;
      const bf16x8 aH = ldfrag(Ph, arow, slot);
      const bf16x8 aL = ldfrag(Pl, arow, slot);
#pragma unroll
      for (int ni = 0; ni < 4; ++ni) {
        const int brow = ni * 16 + r;
        const bf16x8 bH = ldfrag(Vh, brow, slot);
        const bf16x8 bL = ldfrag(Vl, brow, slot);
        acc[ni] = mfma16(aH, bH, acc[ni]);
        acc[ni] = mfma16(aH, bL, acc[ni]);
        acc[ni] = mfma16(aL, bH, acc[ni]);
      }
    }
  }
  const int s0 = blockIdx.x * 64 + wid * 16 + 4 * g;
#pragma unroll
  for (int ni = 0; ni < 4; ++ni) {
    const int d = ni * 16 + r;
#pragma unroll
    for (int j = 0; j < 4; ++j) {
      const int s = s0 + j;
      C[(size_t)(b * S_ + s) * D_ + h * DP_ + d] = acc[ni][j];
    }
  }
}

extern "C" void kernel_launch(void* const* d_in, const int* in_sizes, int n_in,
                              void* d_out, int out_size, void* d_ws, size_t ws_size,
                              hipStream_t stream) {
  (void)in_sizes; (void)n_in; (void)out_size; (void)ws_size;
  const float* q = (const float*)d_in[0];
  const float* k = (const float*)d_in[1];
  const float* v = (const float*)d_in[2];
  const int* mask = (const int*)d_in[3];
  const float* wq_w = (const float*)d_in[4];
  const float* wq_b = (const float*)d_in[5];
  const float* wk_w = (const float*)d_in[6];
  const float* wk_b = (const float*)d_in[7];
  const float* wv_w = (const float*)d_in[8];
  const float* wv_b = (const float*)d_in[9];
  const float* wo_w = (const float*)d_in[10];
  const float* wo_b = (const float*)d_in[11];

  float* out = (float*)d_out;
  float* attn = (float*)d_out + OUT_ELEMS;

  float* qh = (float*)d_ws;            // [B,H,S,64]
  float* kh = qh + HS_ELEMS;           // [B,H,S,64]
  float* vt = kh + HS_ELEMS;           // [B,H,64,S] (transposed V)
  float* ctx = vt + HS_ELEMS;          // [B,S,768] concat layout

  const dim3 gproj(M_ / 128, D_ / 128);
  xwt_mfma<1><<<gproj, 256, 0, stream>>>(q, wq_w, wq_b, qh);
  xwt_mfma<1><<<gproj, 256, 0, stream>>>(k, wk_w, wk_b, kh);
  xwt_mfma<2><<<gproj, 256, 0, stream>>>(v, wv_w, wv_b, vt);

  const dim3 gsc(S_ / 128, S_ / 128, B_ * H_);
  scores_mfma<<<gsc, 256, 0, stream>>>(qh, kh, attn);

  softmax_rows<<<dim3(B_ * H_ * S_), 256, 0, stream>>>(attn, mask);

  const dim3 gctx(S_ / 64, B_ * H_);
  ctx_mfma<<<gctx, 256, 0, stream>>>(attn, vt, ctx);

  xwt_mfma<0><<<gproj, 256, 0, stream>>>(ctx, wo_w, wo_b, out);
}